// Round 5
// baseline (1128.283 us; speedup 1.0000x reference)
//
#include <hip/hip_runtime.h>
#include <stdint.h>
#include <math.h>

#define N_ROWS 131072
#define K_CEN  2048
#define D_DIM  1024
#define BM     64
#define TAU    0.02f
#define CAND_CAP 64

typedef short bf16x8 __attribute__((ext_vector_type(8)));
typedef float f32x4  __attribute__((ext_vector_type(4)));

__device__ __forceinline__ unsigned short f2bf(float f) {
  unsigned u = __float_as_uint(f);
  return (unsigned short)((u + 0x7fffu + ((u >> 16) & 1u)) >> 16);  // RNE
}
__device__ __forceinline__ unsigned f2ord(float f) {
  unsigned u = __float_as_uint(f);
  return (u & 0x80000000u) ? ~u : (u | 0x80000000u);  // monotone float->uint
}
__device__ __forceinline__ float ord2f(unsigned o) {
  unsigned u = (o & 0x80000000u) ? (o & 0x7fffffffu) : ~o;
  return __uint_as_float(u);
}

// ---- prep: centroids fp32 -> bf16 (row-major [K][D]) into ws ----
__global__ __launch_bounds__(256) void cvt_centroids(const float* __restrict__ cen,
                                                     unsigned short* __restrict__ outb) {
  int i = blockIdx.x * 256 + threadIdx.x;           // 524288 threads x 4 floats
  float4 v = reinterpret_cast<const float4*>(cen)[i];
  ushort4 r;
  r.x = f2bf(v.x); r.y = f2bf(v.y); r.z = f2bf(v.z); r.w = f2bf(v.w);
  reinterpret_cast<ushort4*>(outb)[i] = r;
}

// ---- main: A resident in LDS; B streamed L2->regs depth-4; sched_barrier-pinned pipeline.
// Wave w owns cols [w*256, w*256+256), tile 64x64, acc 4x4 of 16x16. Barrier-free K loop.
// LDS (156KB) caps at 1 WG/CU = 2 waves/EU -> tell RA explicitly: budget 256 VGPR, no spill.
__global__
__attribute__((amdgpu_flat_work_group_size(512, 512)))
__attribute__((amdgpu_waves_per_eu(2, 2)))
void assign_rows(
    const float* __restrict__ vec, const float* __restrict__ cenf,
    const unsigned short* __restrict__ cenb, int* __restrict__ out)
{
  __shared__ unsigned short v_lds[BM * D_DIM];      // 128 KB, XOR-swizzled bf16
  __shared__ unsigned rowmax_ord[BM];
  __shared__ int cand_cnt[BM];
  __shared__ unsigned candv[BM][CAND_CAP];          // bf16-dot score (ordered uint)
  __shared__ unsigned short candc[BM][CAND_CAP];    // centroid index

  const int tid  = threadIdx.x;
  const int lane = tid & 63;
  const int wid  = tid >> 6;     // 8 waves, each owns a 256-col strip
  const long row0 = (long)blockIdx.x * BM;

  for (int r = tid; r < BM; r += 512) { rowmax_ord[r] = f2ord(-3.0e38f); cand_cnt[r] = 0; }

  // stage v rows -> swizzled bf16 LDS (64 rows x 1024); non-temporal (protect cenb in L2)
  #pragma unroll
  for (int it = 0; it < 16; ++it) {
    int cid = it * 512 + tid;
    int r  = cid >> 7;                 // 128 chunks of 8 per row
    int dc = (cid & 127) << 3;
    const f32x4* vp = reinterpret_cast<const f32x4*>(vec + (row0 + r) * D_DIM + dc);
    f32x4 a = __builtin_nontemporal_load(vp);
    f32x4 b = __builtin_nontemporal_load(vp + 1);
    bf16x8 pk;
    pk[0]=(short)f2bf(a[0]); pk[1]=(short)f2bf(a[1]); pk[2]=(short)f2bf(a[2]); pk[3]=(short)f2bf(a[3]);
    pk[4]=(short)f2bf(b[0]); pk[5]=(short)f2bf(b[1]); pk[6]=(short)f2bf(b[2]); pk[7]=(short)f2bf(b[3]);
    int byt = (r << 11) + (dc << 1);
    *reinterpret_cast<bf16x8*>(reinterpret_cast<char*>(v_lds) + (byt ^ ((r & 7) << 4))) = pk;
  }
  __syncthreads();

  const int l15 = lane & 15;
  const int lq  = lane >> 4;
  const int amask = (l15 & 7) << 4;                 // lane-constant XOR swizzle
  const int abase = (l15 << 11) + (lq << 4);        // row(l15)*2048 + oct*16 bytes
  const char* v_bytes = reinterpret_cast<const char*>(v_lds);
  const char* c_bytes = reinterpret_cast<const char*>(cenb);

  for (int cb = 0; cb < 4; ++cb) {
    const int colbase = (wid << 8) + (cb << 6);
    const size_t bbase = ((size_t)(colbase + l15) << 11) + (size_t)(lq << 4);
    const char* bp0 = c_bytes + bbase;              // per-ni base ptrs: k-offset fits imm
    const char* bp1 = bp0 + 32768;
    const char* bp2 = bp1 + 32768;
    const char* bp3 = bp2 + 32768;

    f32x4 acc[4][4];
    #pragma unroll
    for (int mi = 0; mi < 4; ++mi)
      #pragma unroll
      for (int ni = 0; ni < 4; ++ni) acc[mi][ni] = (f32x4){0.f,0.f,0.f,0.f};

    bf16x8 breg[4][4];   // [k&3][ni] : depth-4 L2 prefetch
    bf16x8 areg[2][4];   // [k&1][mi] : depth-2 LDS prefetch

    // prologue: B(k=0..3), A(k=0); fence so these cannot be sunk into the loop
    #pragma unroll
    for (int k = 0; k < 4; ++k) {
      breg[k][0] = *reinterpret_cast<const bf16x8*>(bp0 + (k << 6));
      breg[k][1] = *reinterpret_cast<const bf16x8*>(bp1 + (k << 6));
      breg[k][2] = *reinterpret_cast<const bf16x8*>(bp2 + (k << 6));
      breg[k][3] = *reinterpret_cast<const bf16x8*>(bp3 + (k << 6));
    }
    {
      int ta = abase ^ amask;
      #pragma unroll
      for (int mi = 0; mi < 4; ++mi)
        areg[0][mi] = *reinterpret_cast<const bf16x8*>(v_bytes + ta + (mi << 15));
    }
    __builtin_amdgcn_sched_barrier(0);

    #pragma unroll
    for (int kc = 0; kc < 32; ++kc) {
      // phase 1: A(kc+1) from LDS (depth-1 ahead)
      if (kc + 1 < 32) {
        int ta = (abase + ((kc + 1) << 6)) ^ amask;
        #pragma unroll
        for (int mi = 0; mi < 4; ++mi)
          areg[(kc + 1) & 1][mi] = *reinterpret_cast<const bf16x8*>(v_bytes + ta + (mi << 15));
      }
      __builtin_amdgcn_sched_barrier(0);
      // phase 2: MFMA cluster on A(kc), B(kc). SIInsertWaitcnts emits counted
      // vmcnt (stages kc+1..kc+3 outstanding), not vmcnt(0).
      __builtin_amdgcn_s_setprio(1);
      #pragma unroll
      for (int ni = 0; ni < 4; ++ni)
        #pragma unroll
        for (int mi = 0; mi < 4; ++mi)
          acc[mi][ni] = __builtin_amdgcn_mfma_f32_16x16x32_bf16(areg[kc & 1][mi], breg[kc & 3][ni], acc[mi][ni], 0, 0, 0);
      __builtin_amdgcn_s_setprio(0);
      __builtin_amdgcn_sched_barrier(0);
      // phase 3: B(kc+4) from L2 into the slot just consumed (program order after
      // the MFMA reads -> correct; fences keep it from being sunk toward its use)
      if (kc + 4 < 32) {
        const int ko = (kc + 4) << 6;
        breg[kc & 3][0] = *reinterpret_cast<const bf16x8*>(bp0 + ko);
        breg[kc & 3][1] = *reinterpret_cast<const bf16x8*>(bp1 + ko);
        breg[kc & 3][2] = *reinterpret_cast<const bf16x8*>(bp2 + ko);
        breg[kc & 3][3] = *reinterpret_cast<const bf16x8*>(bp3 + ko);
      }
      __builtin_amdgcn_sched_barrier(0);
    }

    // running row-max (C layout: col = l15, row = lq*4+j within 16x16 tile)
    #pragma unroll
    for (int mi = 0; mi < 4; ++mi) {
      #pragma unroll
      for (int j = 0; j < 4; ++j) {
        float mv = fmaxf(fmaxf(acc[mi][0][j], acc[mi][1][j]),
                         fmaxf(acc[mi][2][j], acc[mi][3][j]));
        mv = fmaxf(mv, __shfl_xor(mv, 1));
        mv = fmaxf(mv, __shfl_xor(mv, 2));
        mv = fmaxf(mv, __shfl_xor(mv, 4));
        mv = fmaxf(mv, __shfl_xor(mv, 8));
        if (l15 == 0) {
          int row = (mi << 4) + (lq << 2) + j;
          atomicMax(&rowmax_ord[row], f2ord(mv));
        }
      }
    }
    // candidate append (monotone running max => conservative, never misses)
    #pragma unroll
    for (int mi = 0; mi < 4; ++mi) {
      #pragma unroll
      for (int j = 0; j < 4; ++j) {
        int row = (mi << 4) + (lq << 2) + j;
        float thr = ord2f(rowmax_ord[row]) - TAU;
        #pragma unroll
        for (int ni = 0; ni < 4; ++ni) {
          float v = acc[mi][ni][j];
          if (v >= thr) {
            int slot = atomicAdd(&cand_cnt[row], 1);
            if (slot < CAND_CAP) {
              candv[row][slot] = f2ord(v);
              candc[row][slot] = (unsigned short)(colbase + (ni << 4) + l15);
            }
          }
        }
      }
    }
  }
  __syncthreads();

  // filter vs final row max; single survivor => answer directly (no re-read);
  // multiple => exact fp64 rescore, first-occurrence (lowest col) tie-break.
  for (int r = wid; r < BM; r += 8) {
    const long grow = row0 + r;
    int cnt = cand_cnt[r]; cnt = cnt > CAND_CAP ? CAND_CAP : cnt;
    const unsigned thro = f2ord(ord2f(rowmax_ord[r]) - TAU);

    bool sv = (lane < cnt) && (candv[r][lane] >= thro);
    unsigned long long bal = __ballot(sv);
    int nsurv = __popcll(bal);
    if (nsurv == 1) {
      int idx = __builtin_ctzll(bal);
      if (lane == 0) out[grow] = (int)candc[r][idx];
      continue;
    }
    const bool use_filter = (nsurv >= 1);   // nsurv==0 (CAP overflow pathology): rescore all

    const float* vrow = vec + grow * D_DIM + (lane << 4);
    float va[16];
    #pragma unroll
    for (int i = 0; i < 16; ++i) va[i] = vrow[i];
    double bestv = -1.0e300;
    int    besti = 0x7fffffff;
    for (int ci = 0; ci < cnt; ++ci) {
      if (use_filter && candv[r][ci] < thro) continue;
      const int col = (int)candc[r][ci];
      const float* crow = cenf + ((size_t)col << 10) + (lane << 4);
      double s = 0.0;
      #pragma unroll
      for (int i = 0; i < 16; ++i) s = fma((double)va[i], (double)crow[i], s);
      s += __shfl_xor(s, 32);
      s += __shfl_xor(s, 16);
      s += __shfl_xor(s, 8);
      s += __shfl_xor(s, 4);
      s += __shfl_xor(s, 2);
      s += __shfl_xor(s, 1);
      if (s > bestv || (s == bestv && col < besti)) { bestv = s; besti = col; }
    }
    if (lane == 0) out[grow] = besti;
  }
}

extern "C" void kernel_launch(void* const* d_in, const int* in_sizes, int n_in,
                              void* d_out, int out_size, void* d_ws, size_t ws_size,
                              hipStream_t stream) {
  const float* vec  = (const float*)d_in[0];   // [131072][1024] fp32
  const float* cenf = (const float*)d_in[1];   // [2048][1024] fp32 (pre-normalized)
  unsigned short* cenb = (unsigned short*)d_ws; // 4 MB bf16 centroids
  int* out = (int*)d_out;                      // [131072] int32 assignments

  cvt_centroids<<<(K_CEN * D_DIM / 4) / 256, 256, 0, stream>>>(cenf, cenb);
  assign_rows<<<N_ROWS / BM, 512, 0, stream>>>(vec, cenf, cenb, out);
}

// Round 6
// 1080.522 us; speedup vs baseline: 1.0442x; 1.0442x over previous
//
#include <hip/hip_runtime.h>
#include <stdint.h>
#include <math.h>

#define N_ROWS 131072
#define K_CEN  2048
#define D_DIM  1024
#define BM     64
#define TAU    0.02f
#define CAND_CAP 64

typedef short bf16x8 __attribute__((ext_vector_type(8)));
typedef float f32x4  __attribute__((ext_vector_type(4)));

__device__ __forceinline__ unsigned short f2bf(float f) {
  unsigned u = __float_as_uint(f);
  return (unsigned short)((u + 0x7fffu + ((u >> 16) & 1u)) >> 16);  // RNE
}
__device__ __forceinline__ unsigned f2ord(float f) {
  unsigned u = __float_as_uint(f);
  return (u & 0x80000000u) ? ~u : (u | 0x80000000u);  // monotone float->uint
}
__device__ __forceinline__ float ord2f(unsigned o) {
  unsigned u = (o & 0x80000000u) ? (o & 0x7fffffffu) : ~o;
  return __uint_as_float(u);
}

// ---- prep: centroids fp32 -> bf16 (row-major [K][D]) into ws ----
__global__ __launch_bounds__(256) void cvt_centroids(const float* __restrict__ cen,
                                                     unsigned short* __restrict__ outb) {
  int i = blockIdx.x * 256 + threadIdx.x;           // 524288 threads x 4 floats
  float4 v = reinterpret_cast<const float4*>(cen)[i];
  ushort4 r;
  r.x = f2bf(v.x); r.y = f2bf(v.y); r.z = f2bf(v.z); r.w = f2bf(v.w);
  reinterpret_cast<ushort4*>(outb)[i] = r;
}

// ---- main: A resident in LDS; B streamed L2->regs depth-2 (fits the RA's ~128-VGPR cap,
// no spill); sched_barrier-pinned phases; barrier-free K loop; 2 waves/SIMD TLP.
__global__ __launch_bounds__(512, 1) void assign_rows(
    const float* __restrict__ vec, const float* __restrict__ cenf,
    const unsigned short* __restrict__ cenb, int* __restrict__ out)
{
  __shared__ unsigned short v_lds[BM * D_DIM];      // 128 KB, XOR-swizzled bf16
  __shared__ unsigned rowmax_ord[BM];
  __shared__ int cand_cnt[BM];
  __shared__ unsigned candv[BM][CAND_CAP];          // bf16-dot score (ordered uint)
  __shared__ unsigned short candc[BM][CAND_CAP];    // centroid index

  const int tid  = threadIdx.x;
  const int lane = tid & 63;
  const int wid  = tid >> 6;     // 8 waves, each owns a 256-col strip
  const long row0 = (long)blockIdx.x * BM;

  for (int r = tid; r < BM; r += 512) { rowmax_ord[r] = f2ord(-3.0e38f); cand_cnt[r] = 0; }

  // stage v rows -> swizzled bf16 LDS (64 rows x 1024); non-temporal (protect cenb in L2)
  #pragma unroll
  for (int it = 0; it < 16; ++it) {
    int cid = it * 512 + tid;
    int r  = cid >> 7;                 // 128 chunks of 8 per row
    int dc = (cid & 127) << 3;
    const f32x4* vp = reinterpret_cast<const f32x4*>(vec + (row0 + r) * D_DIM + dc);
    f32x4 a = __builtin_nontemporal_load(vp);
    f32x4 b = __builtin_nontemporal_load(vp + 1);
    bf16x8 pk;
    pk[0]=(short)f2bf(a[0]); pk[1]=(short)f2bf(a[1]); pk[2]=(short)f2bf(a[2]); pk[3]=(short)f2bf(a[3]);
    pk[4]=(short)f2bf(b[0]); pk[5]=(short)f2bf(b[1]); pk[6]=(short)f2bf(b[2]); pk[7]=(short)f2bf(b[3]);
    int byt = (r << 11) + (dc << 1);
    *reinterpret_cast<bf16x8*>(reinterpret_cast<char*>(v_lds) + (byt ^ ((r & 7) << 4))) = pk;
  }
  __syncthreads();

  const int l15 = lane & 15;
  const int lq  = lane >> 4;
  const int amask = (l15 & 7) << 4;                 // lane-constant XOR swizzle
  const int abase = (l15 << 11) + (lq << 4);        // row(l15)*2048 + oct*16 bytes
  const char* v_bytes = reinterpret_cast<const char*>(v_lds);
  const char* c_bytes = reinterpret_cast<const char*>(cenb);

  for (int cb = 0; cb < 4; ++cb) {
    const int colbase = (wid << 8) + (cb << 6);
    const size_t bbase = ((size_t)(colbase + l15) << 11) + (size_t)(lq << 4);
    const char* bp0 = c_bytes + bbase;              // per-ni base ptrs: k-offset fits imm
    const char* bp1 = bp0 + 32768;
    const char* bp2 = bp1 + 32768;
    const char* bp3 = bp2 + 32768;

    f32x4 acc[4][4];
    #pragma unroll
    for (int mi = 0; mi < 4; ++mi)
      #pragma unroll
      for (int ni = 0; ni < 4; ++ni) acc[mi][ni] = (f32x4){0.f,0.f,0.f,0.f};

    bf16x8 breg[2][4];   // [k&1][ni] : depth-2 L2 prefetch (32 VGPR — fits under RA cap)
    bf16x8 areg[2][4];   // [k&1][mi] : depth-2 LDS prefetch

    // prologue: B(k=0), B(k=1), A(k=0); fence so these cannot be sunk into the loop
    breg[0][0] = *reinterpret_cast<const bf16x8*>(bp0);
    breg[0][1] = *reinterpret_cast<const bf16x8*>(bp1);
    breg[0][2] = *reinterpret_cast<const bf16x8*>(bp2);
    breg[0][3] = *reinterpret_cast<const bf16x8*>(bp3);
    breg[1][0] = *reinterpret_cast<const bf16x8*>(bp0 + 64);
    breg[1][1] = *reinterpret_cast<const bf16x8*>(bp1 + 64);
    breg[1][2] = *reinterpret_cast<const bf16x8*>(bp2 + 64);
    breg[1][3] = *reinterpret_cast<const bf16x8*>(bp3 + 64);
    {
      int ta = abase ^ amask;
      #pragma unroll
      for (int mi = 0; mi < 4; ++mi)
        areg[0][mi] = *reinterpret_cast<const bf16x8*>(v_bytes + ta + (mi << 15));
    }
    __builtin_amdgcn_sched_barrier(0);

    #pragma unroll
    for (int kc = 0; kc < 32; ++kc) {
      // phase 1: A(kc+1) from LDS (depth-1 ahead)
      if (kc + 1 < 32) {
        int ta = (abase + ((kc + 1) << 6)) ^ amask;
        #pragma unroll
        for (int mi = 0; mi < 4; ++mi)
          areg[(kc + 1) & 1][mi] = *reinterpret_cast<const bf16x8*>(v_bytes + ta + (mi << 15));
      }
      __builtin_amdgcn_sched_barrier(0);
      // phase 2: MFMA cluster on A(kc), B(kc), with B(kc+2) issue interleaved per-ni
      // right after its WAR dependence (the 4 MFMAs reading breg[kc&1][ni]) clears.
      // Counted vmcnt (not 0) emerges: at most 8 B-loads outstanding.
      __builtin_amdgcn_s_setprio(1);
      #pragma unroll
      for (int ni = 0; ni < 4; ++ni) {
        #pragma unroll
        for (int mi = 0; mi < 4; ++mi)
          acc[mi][ni] = __builtin_amdgcn_mfma_f32_16x16x32_bf16(areg[kc & 1][mi], breg[kc & 1][ni], acc[mi][ni], 0, 0, 0);
        if (kc + 2 < 32) {
          const int ko = (kc + 2) << 6;
          const char* bp = ni==0?bp0: ni==1?bp1: ni==2?bp2: bp3;
          breg[kc & 1][ni] = *reinterpret_cast<const bf16x8*>(bp + ko);
        }
      }
      __builtin_amdgcn_s_setprio(0);
      __builtin_amdgcn_sched_barrier(0);
    }

    // running row-max (C layout: col = l15, row = lq*4+j within 16x16 tile)
    #pragma unroll
    for (int mi = 0; mi < 4; ++mi) {
      #pragma unroll
      for (int j = 0; j < 4; ++j) {
        float mv = fmaxf(fmaxf(acc[mi][0][j], acc[mi][1][j]),
                         fmaxf(acc[mi][2][j], acc[mi][3][j]));
        mv = fmaxf(mv, __shfl_xor(mv, 1));
        mv = fmaxf(mv, __shfl_xor(mv, 2));
        mv = fmaxf(mv, __shfl_xor(mv, 4));
        mv = fmaxf(mv, __shfl_xor(mv, 8));
        if (l15 == 0) {
          int row = (mi << 4) + (lq << 2) + j;
          atomicMax(&rowmax_ord[row], f2ord(mv));
        }
      }
    }
    // candidate append (monotone running max => conservative, never misses)
    #pragma unroll
    for (int mi = 0; mi < 4; ++mi) {
      #pragma unroll
      for (int j = 0; j < 4; ++j) {
        int row = (mi << 4) + (lq << 2) + j;
        float thr = ord2f(rowmax_ord[row]) - TAU;
        #pragma unroll
        for (int ni = 0; ni < 4; ++ni) {
          float v = acc[mi][ni][j];
          if (v >= thr) {
            int slot = atomicAdd(&cand_cnt[row], 1);
            if (slot < CAND_CAP) {
              candv[row][slot] = f2ord(v);
              candc[row][slot] = (unsigned short)(colbase + (ni << 4) + l15);
            }
          }
        }
      }
    }
  }
  __syncthreads();

  // filter vs final row max; single survivor => answer directly (no re-read);
  // multiple => exact fp64 rescore, first-occurrence (lowest col) tie-break.
  for (int r = wid; r < BM; r += 8) {
    const long grow = row0 + r;
    int cnt = cand_cnt[r]; cnt = cnt > CAND_CAP ? CAND_CAP : cnt;
    const unsigned thro = f2ord(ord2f(rowmax_ord[r]) - TAU);

    bool sv = (lane < cnt) && (candv[r][lane] >= thro);
    unsigned long long bal = __ballot(sv);
    int nsurv = __popcll(bal);
    if (nsurv == 1) {
      int idx = __builtin_ctzll(bal);
      if (lane == 0) out[grow] = (int)candc[r][idx];
      continue;
    }
    const bool use_filter = (nsurv >= 1);   // nsurv==0 (CAP overflow pathology): rescore all

    const float* vrow = vec + grow * D_DIM + (lane << 4);
    float va[16];
    #pragma unroll
    for (int i = 0; i < 16; ++i) va[i] = vrow[i];
    double bestv = -1.0e300;
    int    besti = 0x7fffffff;
    for (int ci = 0; ci < cnt; ++ci) {
      if (use_filter && candv[r][ci] < thro) continue;
      const int col = (int)candc[r][ci];
      const float* crow = cenf + ((size_t)col << 10) + (lane << 4);
      double s = 0.0;
      #pragma unroll
      for (int i = 0; i < 16; ++i) s = fma((double)va[i], (double)crow[i], s);
      s += __shfl_xor(s, 32);
      s += __shfl_xor(s, 16);
      s += __shfl_xor(s, 8);
      s += __shfl_xor(s, 4);
      s += __shfl_xor(s, 2);
      s += __shfl_xor(s, 1);
      if (s > bestv || (s == bestv && col < besti)) { bestv = s; besti = col; }
    }
    if (lane == 0) out[grow] = besti;
  }
}

extern "C" void kernel_launch(void* const* d_in, const int* in_sizes, int n_in,
                              void* d_out, int out_size, void* d_ws, size_t ws_size,
                              hipStream_t stream) {
  const float* vec  = (const float*)d_in[0];   // [131072][1024] fp32
  const float* cenf = (const float*)d_in[1];   // [2048][1024] fp32 (pre-normalized)
  unsigned short* cenb = (unsigned short*)d_ws; // 4 MB bf16 centroids
  int* out = (int*)d_out;                      // [131072] int32 assignments

  cvt_centroids<<<(K_CEN * D_DIM / 4) / 256, 256, 0, stream>>>(cenf, cenb);
  assign_rows<<<N_ROWS / BM, 512, 0, stream>>>(vec, cenf, cenb, out);
}